// Round 1
// baseline (542.763 us; speedup 1.0000x reference)
//
#include <hip/hip_runtime.h>
#include <hip/hip_cooperative_groups.h>
#include <math.h>

namespace cg = cooperative_groups;

#define B 16
#define L 512
#define HID 768
#define HEADS 12
#define M 4
#define EMB 768
#define BLK 8
#define NER 6
#define NCLS 97
#define CAT (2*HID + NER)   // 1542
#define EB (EMB*BLK)        // 6144
#define NB 256              // 1 block / CU -> cooperative co-residency guaranteed
#define NT 512
#define NCH 16              // l-chunks for rs phase (16 b x 16 ch = 256 blocks)
#define LCH (L/NCH)         // 32

// ---------------------------------------------------------------------------
// Single cooperative kernel, 4 phases separated by grid.sync():
//  P1: pp[b][h][l] = (sum_m A[b,h,s0m,l])*(sum_m A[b,h,s1m,l]) ; ent logsumexp;
//      zero rs.                         (blocks 0..191 att, 192..207 zero)
//  P2: recombine pp -> normalized ht weights (LDS), accumulate rs partials
//      for 32 l's per block, atomicAdd. (block = b*16+ch, all 256)
//  P3: proj = tanh([ent_e; rs; ner] @ W^T + b), 2 j-rows per wave.
//      (blocks 0..191: jg*4 + t*2 + zh)
//  P4: logits[c] = sum_k Wb[c,k]*hs2[g*8+r]*ts2[g*8+cc] + bb[c]  (bl fused,
//      never materialized). (blocks 0..96)
// Rationale: on-GPU work is ~10-20us at roofline; the 298us came from 5
// serialized dispatches' launch+drain overhead. One dispatch removes it.
// ---------------------------------------------------------------------------
__launch_bounds__(NT)
__global__ void mega(const float* __restrict__ att, const float* __restrict__ seq,
                     const int* __restrict__ epos,
                     const float* __restrict__ hner, const float* __restrict__ tner,
                     const float* __restrict__ Wh, const float* __restrict__ bh,
                     const float* __restrict__ Wt, const float* __restrict__ bt,
                     const float* __restrict__ Wb, const float* __restrict__ bb,
                     float* __restrict__ pp, float* __restrict__ ent,
                     float* __restrict__ rs, float* __restrict__ proj,
                     float* __restrict__ out) {
    cg::grid_group gg = cg::this_grid();
    const int blk = blockIdx.x, tid = threadIdx.x;

    __shared__ int   ss[2][M];
    __shared__ float sraw[L];
    __shared__ float red[8];
    __shared__ float sinv;
    __shared__ float actA[CAT*4];   // 24.1 KB
    __shared__ float actB[CAT*4];   // 24.1 KB  (total ~52 KB < 160 KB)

    // ---------------- Phase 1 -------------------------------------------
    if (blk < B*HEADS) {
        int b = blk / HEADS, h = blk - b*HEADS;
        if (tid < 2*M) {
            int e = tid >> 2, m = tid & 3;
            ss[e][m] = epos[(b*2 + e)*M + m] + 1;
        }
        __syncthreads();

        int l = tid;   // 512 threads = L
        const float* ah = att + ((size_t)b*HEADS + h)*L*L;
        float a0 = 0.f, a1 = 0.f;
        #pragma unroll
        for (int m = 0; m < M; ++m) {
            a0 += ah[(size_t)ss[0][m]*L + l];
            a1 += ah[(size_t)ss[1][m]*L + l];
        }
        pp[((size_t)b*HEADS + h)*L + l] = a0*a1;

        if (h < 2) {
            // ent_emb for entity e=h: logsumexp over M mention rows
            const float* base = seq + (size_t)b*L*HID;
            for (int d = tid; d < HID; d += NT) {
                float v0 = base[(size_t)ss[h][0]*HID + d];
                float v1 = base[(size_t)ss[h][1]*HID + d];
                float v2 = base[(size_t)ss[h][2]*HID + d];
                float v3 = base[(size_t)ss[h][3]*HID + d];
                float mx = fmaxf(fmaxf(v0, v1), fmaxf(v2, v3));
                float s = expf(v0-mx) + expf(v1-mx) + expf(v2-mx) + expf(v3-mx);
                ent[((size_t)h*B + b)*HID + d] = mx + logf(s);
            }
        }
    } else if (blk < B*HEADS + B) {
        int b = blk - B*HEADS;
        for (int d = tid; d < HID; d += NT) rs[b*HID + d] = 0.f;
    }
    __threadfence();
    gg.sync();

    // ---------------- Phase 2 -------------------------------------------
    {
        int b = blk >> 4, ch = blk & (NCH-1);
        // recombine per-head partials (L2-hot) into normalized weights
        int l = tid;
        float r = 0.f;
        #pragma unroll
        for (int h = 0; h < HEADS; ++h) r += pp[((size_t)b*HEADS + h)*L + l];
        r *= (1.f/(M*M*HEADS));
        sraw[l] = r;

        float psum = r;
        for (int off = 32; off; off >>= 1) psum += __shfl_down(psum, off);
        int wid = tid >> 6, lane = tid & 63;
        if (lane == 0) red[wid] = psum;
        __syncthreads();
        if (tid == 0) {
            float s = 0.f;
            #pragma unroll
            for (int w = 0; w < 8; ++w) s += red[w];
            sinv = 1.f/(s + 1e-5f);
        }
        __syncthreads();
        float inv = sinv;

        // rs partial for this block's 32 l's; 384 active threads (2 l-halves)
        if (tid < 384) {
            int lsub = tid / 192, d4 = tid - lsub*192;
            const float4* sp = (const float4*)(seq + (size_t)b*L*HID);
            int l0 = ch*LCH + lsub*(LCH/2);
            float4 acc = make_float4(0.f, 0.f, 0.f, 0.f);
            #pragma unroll
            for (int i = 0; i < LCH/2; ++i) {
                int ll = l0 + i;
                float w = sraw[ll]*inv;
                float4 v = sp[(size_t)ll*(HID/4) + d4];
                acc.x += w*v.x; acc.y += w*v.y; acc.z += w*v.z; acc.w += w*v.w;
            }
            float* rp = rs + b*HID + d4*4;
            atomicAdd(rp+0, acc.x);
            atomicAdd(rp+1, acc.y);
            atomicAdd(rp+2, acc.z);
            atomicAdd(rp+3, acc.w);
        }
    }
    __threadfence();
    gg.sync();

    // ---------------- Phase 3 -------------------------------------------
    if (blk < 192) {
        int jg = blk >> 2, t = (blk >> 1) & 1, zh = blk & 1;
        const float* e0  = ent + (size_t)t*B*HID;
        const float* ner = t ? tner : hner;
        for (int idx = tid; idx < CAT*8; idx += NT) {
            int k = idx >> 3, bi = idx & 7;
            int gb = zh*8 + bi;
            float v;
            if (k < HID)            v = e0[gb*HID + k];
            else if (k < 2*HID)     v = rs[gb*HID + (k - HID)];
            else                    v = ner[gb*NER + (k - 2*HID)];
            if (bi < 4) actA[k*4 + bi] = v; else actB[k*4 + (bi-4)] = v;
        }
        __syncthreads();

        int wid = tid >> 6, lane = tid & 63;
        int j0 = jg*16 + wid*2;                 // this wave: rows j0, j0+1
        const float* wbase = (t ? Wt : Wh);
        const float* w0 = wbase + (size_t)j0*CAT;
        const float* w1 = w0 + CAT;
        float acc0[8], acc1[8];
        #pragma unroll
        for (int b = 0; b < 8; ++b) { acc0[b] = 0.f; acc1[b] = 0.f; }
        for (int i = 0; i < 25; ++i) {
            int k = i*64 + lane;
            if (k < CAT) {
                float wa = w0[k], wb = w1[k];
                float4 a = *(const float4*)&actA[k*4];
                float4 c = *(const float4*)&actB[k*4];
                acc0[0] += wa*a.x; acc0[1] += wa*a.y; acc0[2] += wa*a.z; acc0[3] += wa*a.w;
                acc0[4] += wa*c.x; acc0[5] += wa*c.y; acc0[6] += wa*c.z; acc0[7] += wa*c.w;
                acc1[0] += wb*a.x; acc1[1] += wb*a.y; acc1[2] += wb*a.z; acc1[3] += wb*a.w;
                acc1[4] += wb*c.x; acc1[5] += wb*c.y; acc1[6] += wb*c.z; acc1[7] += wb*c.w;
            }
        }
        for (int off = 32; off; off >>= 1) {
            #pragma unroll
            for (int b = 0; b < 8; ++b) {
                acc0[b] += __shfl_down(acc0[b], off);
                acc1[b] += __shfl_down(acc1[b], off);
            }
        }
        if (lane == 0) {
            float bj0 = (t ? bt : bh)[j0];
            float bj1 = (t ? bt : bh)[j0+1];
            #pragma unroll
            for (int b = 0; b < 8; ++b) {
                size_t row = ((size_t)t*B + zh*8 + b)*EMB;
                proj[row + j0]     = tanhf(acc0[b] + bj0);
                proj[row + j0 + 1] = tanhf(acc1[b] + bj1);
            }
        }
    }
    __threadfence();
    gg.sync();

    // ---------------- Phase 4 -------------------------------------------
    if (blk < NCLS) {
        int c = blk;
        const float4* wr = (const float4*)(Wb + (size_t)c*EB);
        const float* ph = proj;                   // hs2 [B][EMB]
        const float* pt = proj + (size_t)B*EMB;   // ts2 [B][EMB]
        float acc[B];
        #pragma unroll
        for (int b = 0; b < B; ++b) acc[b] = 0.f;
        for (int i = tid; i < EB/4; i += NT) {    // 3 iters
            float4 w = wr[i];
            int k  = i*4;
            int g8 = (k >> 6)*8;
            int r  = (k >> 3) & 7;
            int c0 = k & 7;                        // 0 or 4
            #pragma unroll
            for (int b = 0; b < B; ++b) {
                float pr = ph[b*EMB + g8 + r];
                float4 q = *(const float4*)(pt + b*EMB + g8 + c0);
                acc[b] += pr*(w.x*q.x + w.y*q.y + w.z*q.z + w.w*q.w);
            }
        }
        int wid = tid >> 6, lane = tid & 63;
        for (int off = 32; off; off >>= 1) {
            #pragma unroll
            for (int b = 0; b < B; ++b) acc[b] += __shfl_down(acc[b], off);
        }
        __shared__ float partl[8][B];
        if (lane == 0) {
            #pragma unroll
            for (int b = 0; b < B; ++b) partl[wid][b] = acc[b];
        }
        __syncthreads();
        if (tid < B) {
            int b = tid;
            float s = 0.f;
            #pragma unroll
            for (int w = 0; w < 8; ++w) s += partl[w][b];
            out[b*NCLS + c] = s + bb[c];
        }
    }
}

extern "C" void kernel_launch(void* const* d_in, const int* in_sizes, int n_in,
                              void* d_out, int out_size, void* d_ws, size_t ws_size,
                              hipStream_t stream) {
    const float* seq  = (const float*)d_in[0];
    const float* att  = (const float*)d_in[1];
    const int*   epos = (const int*)  d_in[2];
    const float* hner = (const float*)d_in[3];
    const float* tner = (const float*)d_in[4];
    const float* Wh   = (const float*)d_in[5];
    const float* bh   = (const float*)d_in[6];
    const float* Wt   = (const float*)d_in[7];
    const float* bt   = (const float*)d_in[8];
    const float* Wb   = (const float*)d_in[9];
    const float* bb   = (const float*)d_in[10];
    float* out = (float*)d_out;

    // ws (floats): pp[B*HEADS*L] | ent[2*B*HID] | rs[B*HID] | proj[2*B*EMB]
    float* ws   = (float*)d_ws;
    float* pp   = ws;
    float* ent  = pp   + (size_t)B*HEADS*L;
    float* rs   = ent  + 2*B*HID;
    float* proj = rs   + B*HID;

    void* kargs[] = {
        (void*)&att, (void*)&seq, (void*)&epos,
        (void*)&hner, (void*)&tner,
        (void*)&Wh, (void*)&bh, (void*)&Wt, (void*)&bt,
        (void*)&Wb, (void*)&bb,
        (void*)&pp, (void*)&ent, (void*)&rs, (void*)&proj, (void*)&out
    };
    hipLaunchCooperativeKernel((void*)mega, dim3(NB), dim3(NT), kargs, 0, stream);
}

// Round 2
// 300.935 us; speedup vs baseline: 1.8036x; 1.8036x over previous
//
#include <hip/hip_runtime.h>
#include <math.h>

#define B 16
#define L 512
#define HID 768
#define HEADS 12
#define M 4
#define EMB 768
#define BLK 8
#define NER 6
#define NCLS 97
#define CAT (2*HID + NER)   // 1542
#define EB (EMB*BLK)        // 6144
#define NCH 16              // l-chunks for rs (B*NCH = 256 blocks -> all CUs)
#define LCH (L/NCH)         // 32

// ---------------------------------------------------------------------------
// K1: grid (B, HEADS), 512 thr. Per-head attention partial product
//     pp[b][h][l] = (sum_m A[b,h,s0m,l]) * (sum_m A[b,h,s1m,l])   (unscaled)
//     Side jobs on spare y-blocks: h<2 -> ent_emb (logsumexp, e=h);
//     h==2 -> zero rs for the atomics in K2.
// ---------------------------------------------------------------------------
__global__ void k_att(const float* __restrict__ att, const float* __restrict__ seq,
                      const int* __restrict__ epos,
                      float* __restrict__ pp, float* __restrict__ ent,
                      float* __restrict__ rs) {
    int b = blockIdx.x, h = blockIdx.y;
    __shared__ int ss[2][M];
    if (threadIdx.x < 2*M) {
        int e = threadIdx.x >> 2, m = threadIdx.x & 3;
        ss[e][m] = epos[(b*2+e)*M + m] + 1;
    }
    __syncthreads();

    int l = threadIdx.x;   // 512 threads = L
    const float* ah = att + ((size_t)b*HEADS + h)*L*L;
    float a0 = 0.f, a1 = 0.f;
    #pragma unroll
    for (int m = 0; m < M; ++m) {
        a0 += ah[(size_t)ss[0][m]*L + l];
        a1 += ah[(size_t)ss[1][m]*L + l];
    }
    pp[((size_t)b*HEADS + h)*L + l] = a0*a1;

    if (h < 2) {
        // ent_emb for entity e=h: logsumexp over M mention rows
        const float* base = seq + (size_t)b*L*HID;
        for (int d = threadIdx.x; d < HID; d += 512) {
            float v0 = base[(size_t)ss[h][0]*HID + d];
            float v1 = base[(size_t)ss[h][1]*HID + d];
            float v2 = base[(size_t)ss[h][2]*HID + d];
            float v3 = base[(size_t)ss[h][3]*HID + d];
            float mx = fmaxf(fmaxf(v0, v1), fmaxf(v2, v3));
            float s = expf(v0-mx) + expf(v1-mx) + expf(v2-mx) + expf(v3-mx);
            ent[((size_t)h*B + b)*HID + d] = mx + logf(s);
        }
    } else if (h == 2) {
        for (int d = threadIdx.x; d < HID; d += 512) rs[b*HID + d] = 0.f;
    }
}

// ---------------------------------------------------------------------------
// K2: grid (B, NCH), 192 thr. Recombine per-head partials (L2/L3-hot) into
//     normalized ht weights in LDS, then accumulate rs partials for this
//     block's 32 l's with float4 loads; atomicAdd into rs[b][d].
//     NCH=16 -> 256 blocks: every CU participates in the 25 MB seq read.
// ---------------------------------------------------------------------------
__launch_bounds__(192)
__global__ void k_rs(const float* __restrict__ seq, const float* __restrict__ pp,
                     float* __restrict__ rs) {
    int b = blockIdx.x, ch = blockIdx.y;
    __shared__ float sraw[L];
    __shared__ float red[3];
    __shared__ float sinv;
    float psum = 0.f;
    for (int l = threadIdx.x; l < L; l += 192) {
        float r = 0.f;
        #pragma unroll
        for (int h = 0; h < HEADS; ++h) r += pp[((size_t)b*HEADS + h)*L + l];
        r *= (1.f/(M*M*HEADS));
        sraw[l] = r;
        psum += r;
    }
    for (int off = 32; off; off >>= 1) psum += __shfl_down(psum, off);
    int wid = threadIdx.x >> 6, lane = threadIdx.x & 63;
    if (lane == 0) red[wid] = psum;
    __syncthreads();
    if (threadIdx.x == 0) sinv = 1.f/(red[0] + red[1] + red[2] + 1e-5f);
    __syncthreads();
    float inv = sinv;

    const float4* sp = (const float4*)(seq + (size_t)b*L*HID + (size_t)ch*LCH*HID);
    float4 acc = make_float4(0.f, 0.f, 0.f, 0.f);
    for (int i = 0; i < LCH; ++i) {
        float w = sraw[ch*LCH + i] * inv;
        float4 v = sp[i*(HID/4) + threadIdx.x];
        acc.x += v.x*w; acc.y += v.y*w; acc.z += v.z*w; acc.w += v.w*w;
    }
    float* rp = rs + b*HID + threadIdx.x*4;
    atomicAdd(rp+0, acc.x);
    atomicAdd(rp+1, acc.y);
    atomicAdd(rp+2, acc.z);
    atomicAdd(rp+3, acc.w);
}

// ---------------------------------------------------------------------------
// K3: hs2/ts2 = tanh([ent_e; rs; ner] @ W^T + b). Grid (EMB/8, 2, 2).
//     Activations transposed in LDS as actA/actB[k][4] so the 8-batch inner
//     read is 2 conflict-free ds_read_b128 per k.
// ---------------------------------------------------------------------------
__launch_bounds__(512)
__global__ void k_proj(const float* __restrict__ Wh, const float* __restrict__ bh,
                       const float* __restrict__ Wt, const float* __restrict__ bt,
                       const float* __restrict__ ent, const float* __restrict__ rs,
                       const float* __restrict__ hner, const float* __restrict__ tner,
                       float* __restrict__ out) {
    int t = blockIdx.y, zh = blockIdx.z;
    __shared__ float actA[CAT*4];   // batches zh*8 + 0..3
    __shared__ float actB[CAT*4];   // batches zh*8 + 4..7
    const float* e0  = ent + (size_t)t*B*HID;
    const float* ner = t ? tner : hner;
    for (int idx = threadIdx.x; idx < CAT*8; idx += 512) {
        int k = idx >> 3, bi = idx & 7;
        int gb = zh*8 + bi;
        float v;
        if (k < HID)            v = e0[gb*HID + k];
        else if (k < 2*HID)     v = rs[gb*HID + (k - HID)];
        else                    v = ner[gb*NER + (k - 2*HID)];
        if (bi < 4) actA[k*4 + bi] = v; else actB[k*4 + bi - 4] = v;
    }
    __syncthreads();

    int wid = threadIdx.x >> 6, lane = threadIdx.x & 63;
    int j = blockIdx.x*8 + wid;
    const float* wrow = (t ? Wt : Wh) + (size_t)j*CAT;
    float acc[8];
    #pragma unroll
    for (int b = 0; b < 8; ++b) acc[b] = 0.f;
    for (int i = 0; i < 25; ++i) {
        int k = i*64 + lane;
        if (k < CAT) {
            float w = wrow[k];
            float4 a = *(const float4*)&actA[k*4];
            float4 c = *(const float4*)&actB[k*4];
            acc[0] += w*a.x; acc[1] += w*a.y; acc[2] += w*a.z; acc[3] += w*a.w;
            acc[4] += w*c.x; acc[5] += w*c.y; acc[6] += w*c.z; acc[7] += w*c.w;
        }
    }
    for (int off = 32; off; off >>= 1)
        #pragma unroll
        for (int b = 0; b < 8; ++b) acc[b] += __shfl_down(acc[b], off);
    if (lane == 0) {
        float bj = (t ? bt : bh)[j];
        #pragma unroll
        for (int b = 0; b < 8; ++b)
            out[((size_t)t*B + zh*8 + b)*EMB + j] = tanhf(acc[b] + bj);
    }
}

// ---------------------------------------------------------------------------
// K4: logits = (bl @ Wb^T + bb) with bl fused algebraically:
//     bl[b, g*64 + r*8 + cc] = hs2[b, g*8+r] * ts2[b, g*8+cc]
//     -> acc[b] += hs2[g8+r] * dot(w4, ts2[g8+c0..c0+3]).  One block/class;
//     Wb read once from HBM, proj L2-hot; bl never materialized.
// ---------------------------------------------------------------------------
__launch_bounds__(512)
__global__ void k_logits(const float* __restrict__ Wb, const float* __restrict__ bb,
                         const float* __restrict__ proj, float* __restrict__ out) {
    int c = blockIdx.x;
    const float4* wr = (const float4*)(Wb + (size_t)c*EB);
    const float* ph = proj;                   // hs2 [B][EMB]
    const float* pt = proj + (size_t)B*EMB;   // ts2 [B][EMB]
    float acc[B];
    #pragma unroll
    for (int b = 0; b < B; ++b) acc[b] = 0.f;
    for (int i = threadIdx.x; i < EB/4; i += 512) {   // 3 iters
        float4 w = wr[i];
        int k  = i*4;
        int g8 = (k >> 6)*8;
        int r  = (k >> 3) & 7;
        int c0 = k & 7;                        // 0 or 4
        #pragma unroll
        for (int b = 0; b < B; ++b) {
            float pr = ph[b*EMB + g8 + r];
            float4 q = *(const float4*)(pt + b*EMB + g8 + c0);
            acc[b] += pr*(w.x*q.x + w.y*q.y + w.z*q.z + w.w*q.w);
        }
    }
    int wid = threadIdx.x >> 6, lane = threadIdx.x & 63;
    for (int off = 32; off; off >>= 1)
        #pragma unroll
        for (int b = 0; b < B; ++b) acc[b] += __shfl_down(acc[b], off);
    __shared__ float partl[8][B];
    if (lane == 0)
        #pragma unroll
        for (int b = 0; b < B; ++b) partl[wid][b] = acc[b];
    __syncthreads();
    if (threadIdx.x < B) {
        int b = threadIdx.x;
        float s = 0.f;
        #pragma unroll
        for (int w = 0; w < 8; ++w) s += partl[w][b];
        out[b*NCLS + c] = s + bb[c];
    }
}

extern "C" void kernel_launch(void* const* d_in, const int* in_sizes, int n_in,
                              void* d_out, int out_size, void* d_ws, size_t ws_size,
                              hipStream_t stream) {
    const float* seq  = (const float*)d_in[0];
    const float* att  = (const float*)d_in[1];
    const int*   epos = (const int*)  d_in[2];
    const float* hner = (const float*)d_in[3];
    const float* tner = (const float*)d_in[4];
    const float* Wh   = (const float*)d_in[5];
    const float* bh   = (const float*)d_in[6];
    const float* Wt   = (const float*)d_in[7];
    const float* bt   = (const float*)d_in[8];
    const float* Wb   = (const float*)d_in[9];
    const float* bb   = (const float*)d_in[10];
    float* out = (float*)d_out;

    // ws (floats): pp[B*HEADS*L] | ent[2*B*HID] | rs[B*HID] | proj[2*B*EMB]
    float* ws   = (float*)d_ws;
    float* pp   = ws;
    float* ent  = pp   + (size_t)B*HEADS*L;
    float* rs   = ent  + 2*B*HID;
    float* proj = rs   + B*HID;

    k_att   <<<dim3(B, HEADS), 512, 0, stream>>>(att, seq, epos, pp, ent, rs);
    k_rs    <<<dim3(B, NCH),   192, 0, stream>>>(seq, pp, rs);
    k_proj  <<<dim3(EMB/8, 2, 2), 512, 0, stream>>>(Wh, bh, Wt, bt, ent, rs, hner, tner, proj);
    k_logits<<<dim3(NCLS),     512, 0, stream>>>(Wb, bb, proj, out);
}